// Round 2
// baseline (785.829 us; speedup 1.0000x reference)
//
#include <hip/hip_runtime.h>
#include <stdint.h>

// Problem geometry (fixed by reference): a = [64,3,768,768] f32
#define BATCH 64
#define PIX   589824      // 768*768 pixels per image
#define PIX4  147456      // PIX/4 (float4 units)
#define IMG3  442368      // 3*PIX4 (float4 stride per image in a)
#define N_TOT 37748736    // BATCH*PIX  (output elements)
#define N4    9437184     // N_TOT/4
#define BPI   144         // K1 blocks per image
#define NPART (BATCH*BPI) // 9216 partials

__device__ __forceinline__ uint32_t rotl32(uint32_t x, int r) {
    return (x << r) | (x >> (32 - r));
}

// Threefry-2x32, 20 rounds, key = (0,1)  [jax.random.key(1)]
__device__ __forceinline__ void threefry01(uint32_t x0, uint32_t x1,
                                           uint32_t& o0, uint32_t& o1) {
    const uint32_t ks0 = 0u, ks1 = 1u, ks2 = 0x1BD11BDBu; // 0x1BD11BDA ^ 0 ^ 1
    x0 += ks0; x1 += ks1;
#define RND(r) { x0 += x1; x1 = rotl32(x1, (r)); x1 ^= x0; }
    RND(13) RND(15) RND(26) RND(6)   x0 += ks1; x1 += ks2 + 1u;
    RND(17) RND(29) RND(16) RND(24)  x0 += ks2; x1 += ks0 + 2u;
    RND(13) RND(15) RND(26) RND(6)   x0 += ks0; x1 += ks1 + 3u;
    RND(17) RND(29) RND(16) RND(24)  x0 += ks1; x1 += ks2 + 4u;
    RND(13) RND(15) RND(26) RND(6)   x0 += ks2; x1 += ks0 + 5u;
#undef RND
    o0 = x0; o1 = x1;
}

// Partitionable threefry 32-bit draw for element index i (< 2^32):
// counter = (hi=0, lo=i); bits = word0 ^ word1.
__device__ __forceinline__ uint32_t jax_bits32(uint32_t i) {
    uint32_t w0, w1;
    threefry01(0u, i, w0, w1);
    return w0 ^ w1;
}

// bits -> uniform[-0.99999994, 1) -> 0.01 * sqrt(2)*erfinv(u)  (XLA-matching)
__device__ __forceinline__ float noise_from_bits(uint32_t bits) {
    float f = __uint_as_float((bits >> 9) | 0x3f800000u) - 1.0f; // [0,1)
    const float LO = __uint_as_float(0xBF7FFFFFu);               // nextafter(-1,0)
    // (maxval-minval) rounds to exactly 2.0f in f32
    float u = fmaxf(LO, fmaf(f, 2.0f, LO));
    // XLA ErfInv32 (Giles): w = -log1p(-u*u)
    float w  = -log1pf(-u * u);
    float ws = w - 2.5f;
    float wb = sqrtf(w) - 3.0f;
    float p1 = 2.81022636e-08f;
    p1 = fmaf(p1, ws, 3.43273939e-07f);
    p1 = fmaf(p1, ws, -3.5233877e-06f);
    p1 = fmaf(p1, ws, -4.39150654e-06f);
    p1 = fmaf(p1, ws, 0.00021858087f);
    p1 = fmaf(p1, ws, -0.00125372503f);
    p1 = fmaf(p1, ws, -0.00417768164f);
    p1 = fmaf(p1, ws, 0.246640727f);
    p1 = fmaf(p1, ws, 1.50140941f);
    float p2 = -0.000200214257f;
    p2 = fmaf(p2, wb, 0.000100950558f);
    p2 = fmaf(p2, wb, 0.00134934322f);
    p2 = fmaf(p2, wb, -0.00367342844f);
    p2 = fmaf(p2, wb, 0.00573950773f);
    p2 = fmaf(p2, wb, -0.0076224613f);
    p2 = fmaf(p2, wb, 0.00943887047f);
    p2 = fmaf(p2, wb, 1.00167406f);
    p2 = fmaf(p2, wb, 2.83297682f);
    float p = (w < 5.0f) ? p1 : p2;
    return 0.01f * 1.41421354f * (p * u);
}

// K1: channel mean + per-block {min,max,sum} partials; optionally store g.
template <bool STORE_G>
__global__ __launch_bounds__(256) void k1_reduce(
    const float* __restrict__ a, float* __restrict__ gbuf,
    float* __restrict__ pmin, float* __restrict__ pmax, float* __restrict__ psum) {
    const int b = blockIdx.y;
    const int tid = threadIdx.x;
    const float4* a4 = (const float4*)a;
    float4* g4 = (float4*)gbuf;
    const int base = b * IMG3;
    const int chunk = blockIdx.x * (256 * 4);
    const float inv3 = 1.0f / 3.0f;
    float mn = 1e30f, mx = -1e30f, sm = 0.0f;
#pragma unroll
    for (int j = 0; j < 4; ++j) {
        int p4 = chunk + j * 256 + tid;
        float4 c0 = a4[base + p4];
        float4 c1 = a4[base + PIX4 + p4];
        float4 c2 = a4[base + 2 * PIX4 + p4];
        float4 g;
        g.x = (c0.x + c1.x + c2.x) * inv3;
        g.y = (c0.y + c1.y + c2.y) * inv3;
        g.z = (c0.z + c1.z + c2.z) * inv3;
        g.w = (c0.w + c1.w + c2.w) * inv3;
        if (STORE_G) g4[b * PIX4 + p4] = g;
        mn = fminf(mn, fminf(fminf(g.x, g.y), fminf(g.z, g.w)));
        mx = fmaxf(mx, fmaxf(fmaxf(g.x, g.y), fmaxf(g.z, g.w)));
        sm += (g.x + g.y) + (g.z + g.w);
    }
#pragma unroll
    for (int off = 32; off; off >>= 1) {
        mn = fminf(mn, __shfl_down(mn, off));
        mx = fmaxf(mx, __shfl_down(mx, off));
        sm += __shfl_down(sm, off);
    }
    __shared__ float smn[4], smx[4], ssm[4];
    int wave = tid >> 6, lane = tid & 63;
    if (lane == 0) { smn[wave] = mn; smx[wave] = mx; ssm[wave] = sm; }
    __syncthreads();
    if (tid == 0) {
        mn = fminf(fminf(smn[0], smn[1]), fminf(smn[2], smn[3]));
        mx = fmaxf(fmaxf(smx[0], smx[1]), fmaxf(smx[2], smx[3]));
        sm = (ssm[0] + ssm[1]) + (ssm[2] + ssm[3]);
        int pi = b * BPI + blockIdx.x;
        pmin[pi] = mn; pmax[pi] = mx; psum[pi] = sm;
    }
}

// K2: fold 144 partials per image -> per-image (scale, bias) with invert folded in.
__global__ __launch_bounds__(64) void k2_finalize(
    const float* __restrict__ pmin, const float* __restrict__ pmax,
    const float* __restrict__ psum, float2* __restrict__ stats) {
    const int b = blockIdx.x;
    const int t = threadIdx.x;
    float mn = 1e30f, mx = -1e30f;
    double sm = 0.0;
    for (int k = t; k < BPI; k += 64) {
        mn = fminf(mn, pmin[b * BPI + k]);
        mx = fmaxf(mx, pmax[b * BPI + k]);
        sm += (double)psum[b * BPI + k];
    }
#pragma unroll
    for (int off = 32; off; off >>= 1) {
        mn = fminf(mn, __shfl_down(mn, off));
        mx = fmaxf(mx, __shfl_down(mx, off));
        sm += __shfl_down(sm, off);
    }
    if (t == 0) {
        float div = fmaxf(0.5f, mx - mn);
        float mean_norm = (float)((sm / (double)PIX - (double)mn) / (double)div);
        float s, tt;
        if (mean_norm > 0.5f) { s = -1.0f / div; tt = 1.0f + mn / div; }
        else                  { s =  1.0f / div; tt = -mn / div; }
        stats[b] = make_float2(s, tt);
    }
}

// K3: out = clip(s*g + t + noise, 0, 1), one float4 per thread,
// partitionable-threefry noise per element.
template <bool USE_G>
__global__ __launch_bounds__(256) void k3_apply(
    const float* __restrict__ a, const float* __restrict__ gbuf,
    const float2* __restrict__ stats, float* __restrict__ out) {
    const int gt = blockIdx.x * 256 + threadIdx.x; // f4 index in [0, N4)
    const int b = gt / PIX4;                       // image index (blocks never straddle)
    const float2 st = stats[b];

    float4 g;
    if (USE_G) {
        g = ((const float4*)gbuf)[gt];
    } else {
        const float4* a4 = (const float4*)a;
        const int pf = gt - b * PIX4;
        const int ab = b * IMG3;
        const float inv3 = 1.0f / 3.0f;
        float4 c0 = a4[ab + pf], c1 = a4[ab + PIX4 + pf], c2 = a4[ab + 2 * PIX4 + pf];
        g.x = (c0.x + c1.x + c2.x) * inv3; g.y = (c0.y + c1.y + c2.y) * inv3;
        g.z = (c0.z + c1.z + c2.z) * inv3; g.w = (c0.w + c1.w + c2.w) * inv3;
    }

    const uint32_t i = (uint32_t)gt * 4u;
    float n0 = noise_from_bits(jax_bits32(i + 0u));
    float n1 = noise_from_bits(jax_bits32(i + 1u));
    float n2 = noise_from_bits(jax_bits32(i + 2u));
    float n3 = noise_from_bits(jax_bits32(i + 3u));

    float4 o;
    o.x = fminf(fmaxf(fmaf(st.x, g.x, st.y) + n0, 0.0f), 1.0f);
    o.y = fminf(fmaxf(fmaf(st.x, g.y, st.y) + n1, 0.0f), 1.0f);
    o.z = fminf(fmaxf(fmaf(st.x, g.z, st.y) + n2, 0.0f), 1.0f);
    o.w = fminf(fmaxf(fmaf(st.x, g.w, st.y) + n3, 0.0f), 1.0f);

    ((float4*)out)[gt] = o;
}

extern "C" void kernel_launch(void* const* d_in, const int* in_sizes, int n_in,
                              void* d_out, int out_size, void* d_ws, size_t ws_size,
                              hipStream_t stream) {
    const float* a = (const float*)d_in[0];
    float* out = (float*)d_out;

    // ws layout (floats): [0,128): stats float2[64]
    //                     [128, 128+3*NPART): pmin/pmax/psum
    //                     [27776, ...): g buffer (float4-aligned), if it fits
    float2* stats = (float2*)d_ws;
    float* pmin = (float*)d_ws + 128;
    float* pmax = pmin + NPART;
    float* psum = pmax + NPART;
    float* gbuf = (float*)d_ws + 27776;
    const bool store_g = ws_size >= (size_t)27776 * 4 + (size_t)N_TOT * 4;

    if (store_g)
        k1_reduce<true><<<dim3(BPI, BATCH), 256, 0, stream>>>(a, gbuf, pmin, pmax, psum);
    else
        k1_reduce<false><<<dim3(BPI, BATCH), 256, 0, stream>>>(a, gbuf, pmin, pmax, psum);

    k2_finalize<<<BATCH, 64, 0, stream>>>(pmin, pmax, psum, stats);

    if (store_g)
        k3_apply<true><<<N4 / 256, 256, 0, stream>>>(a, gbuf, stats, out);
    else
        k3_apply<false><<<N4 / 256, 256, 0, stream>>>(a, gbuf, stats, out);
}